// Round 1
// baseline (894.214 us; speedup 1.0000x reference)
//
#include <hip/hip_runtime.h>
#include <hip/hip_bf16.h>
#include <stdint.h>

// GATv2 x2 fused pipeline, fp32 end-to-end.
// N=50000 nodes, E=800000 edges, 128 -> 256 -> 32, mean over nodes -> [32].

#define NN 50000
#define NE 800000
#define DIN 128
#define DE 16
#define HID 256
#define OUTD 32
#define SLOPE 0.2f

// ---------------- CSR build ----------------

__global__ void k_count(const int* __restrict__ dstv, int* __restrict__ deg) {
  int e = blockIdx.x * 256 + threadIdx.x;
  if (e < NE) atomicAdd(&deg[dstv[e]], 1);
}

__global__ __launch_bounds__(1024) void k_scan(const int* __restrict__ deg,
                                               int* __restrict__ rowptr) {
  __shared__ int lds[1024];
  const int t = threadIdx.x;
  const int CH = 49;  // ceil(50000/1024)
  const int base = t * CH;
  int s = 0;
  for (int i = 0; i < CH; ++i) {
    int idx = base + i;
    if (idx < NN) s += deg[idx];
  }
  lds[t] = s;
  __syncthreads();
  int v = s;
  for (int off = 1; off < 1024; off <<= 1) {
    int add = (t >= off) ? lds[t - off] : 0;
    __syncthreads();
    v += add;
    lds[t] = v;
    __syncthreads();
  }
  int run = v - s;  // exclusive prefix
  for (int i = 0; i < CH; ++i) {
    int idx = base + i;
    if (idx < NN) {
      rowptr[idx] = run;
      run += deg[idx];
    }
  }
  if (t == 1023) rowptr[NN] = run;
}

__global__ void k_fill(const int* __restrict__ dstv, const int* __restrict__ rowptr,
                       int* __restrict__ fill, int* __restrict__ csr) {
  int e = blockIdx.x * 256 + threadIdx.x;
  if (e < NE) {
    int d = dstv[e];
    int p = atomicAdd(&fill[d], 1);
    csr[rowptr[d] + p] = e;
  }
}

// self-loop attr = mean of incoming edge_attr (0 if no in-edges)
__global__ void k_loopattr(const float* __restrict__ ea, const int* __restrict__ rowptr,
                           const int* __restrict__ csr, float* __restrict__ loopat) {
  int g = blockIdx.x * 256 + threadIdx.x;
  if (g >= NN * DE) return;
  int n = g >> 4, d = g & 15;
  int r0 = rowptr[n], r1 = rowptr[n + 1];
  float s = 0.f;
  for (int j = r0; j < r1; ++j) {
    int e = csr[j];
    s += ea[(size_t)e * DE + d];
  }
  int dg = r1 - r0;
  loopat[g] = s / (float)(dg > 0 ? dg : 1);
}

// ---------------- layer-1 node transforms: xl1 = x@Wl1+bl1, xr1 = x@Wr1+br1 ----------------
// block: 256 threads = 256 output cols; 16 rows per block. x loads are block-uniform -> s_load.

__global__ __launch_bounds__(256) void k_xform1(const float* __restrict__ x,
                                                const float* __restrict__ Wl,
                                                const float* __restrict__ bl,
                                                const float* __restrict__ Wr,
                                                const float* __restrict__ br,
                                                float* __restrict__ xl,
                                                float* __restrict__ xr) {
  const int c = threadIdx.x;
  const int r0 = blockIdx.x * 16;
  float accl[16], accr[16];
#pragma unroll
  for (int r = 0; r < 16; ++r) { accl[r] = 0.f; accr[r] = 0.f; }
  const float* __restrict__ xb = x + (size_t)r0 * DIN;
#pragma unroll 4
  for (int k = 0; k < DIN; ++k) {
    const float wl = Wl[k * HID + c];
    const float wr = Wr[k * HID + c];
#pragma unroll
    for (int r = 0; r < 16; ++r) {
      const float xv = xb[r * DIN + k];
      accl[r] = fmaf(xv, wl, accl[r]);
      accr[r] = fmaf(xv, wr, accr[r]);
    }
  }
  const float blc = bl[c], brc = br[c];
#pragma unroll
  for (int r = 0; r < 16; ++r) {
    xl[(size_t)(r0 + r) * HID + c] = accl[r] + blc;
    xr[(size_t)(r0 + r) * HID + c] = accr[r] + brc;
  }
}

// ---------------- layer-1 fused edge kernel: wave per node, online softmax ----------------

__global__ __launch_bounds__(256) void k_edge1(
    const float* __restrict__ xl, const float* __restrict__ xr,
    const float* __restrict__ eattr, const float* __restrict__ loopat,
    const int* __restrict__ srcv, const int* __restrict__ rowptr,
    const int* __restrict__ csr, const float* __restrict__ We,
    const float* __restrict__ att, const float* __restrict__ bias,
    float* __restrict__ hout) {
  const int tid = threadIdx.x;
  const int lane = tid & 63;
  const int wid = tid >> 6;
  const int node = blockIdx.x * 4 + wid;
  const int c0 = lane << 2;  // 4 channels per lane

  // We1 slice in registers: we[k][0..3] (64 VGPRs)
  float we[DE][4];
#pragma unroll
  for (int k = 0; k < DE; ++k) {
    const float4 w4 = *(const float4*)(We + k * HID + c0);
    we[k][0] = w4.x; we[k][1] = w4.y; we[k][2] = w4.z; we[k][3] = w4.w;
  }
  const float4 attv = *(const float4*)(att + c0);
  const float4 xrv = *(const float4*)(xr + (size_t)node * HID + c0);
  const int r0 = rowptr[node], r1 = rowptr[node + 1];

  float m = -3.0e38f, ssum = 0.f;
  float a0 = 0.f, a1 = 0.f, a2 = 0.f, a3 = 0.f;

  auto process = [&](int src, const float* __restrict__ eap) {
    const float4 xs = *(const float4*)(xl + (size_t)src * HID + c0);
    float e0 = 0.f, e1 = 0.f, e2 = 0.f, e3 = 0.f;
#pragma unroll
    for (int k = 0; k < DE; ++k) {
      const float a = eap[k];  // wave-uniform -> scalar load
      e0 = fmaf(a, we[k][0], e0);
      e1 = fmaf(a, we[k][1], e1);
      e2 = fmaf(a, we[k][2], e2);
      e3 = fmaf(a, we[k][3], e3);
    }
    float z0 = xs.x + xrv.x + e0;
    float z1 = xs.y + xrv.y + e1;
    float z2 = xs.z + xrv.z + e2;
    float z3 = xs.w + xrv.w + e3;
    z0 = z0 > 0.f ? z0 : SLOPE * z0;
    z1 = z1 > 0.f ? z1 : SLOPE * z1;
    z2 = z2 > 0.f ? z2 : SLOPE * z2;
    z3 = z3 > 0.f ? z3 : SLOPE * z3;
    float p = z0 * attv.x;
    p = fmaf(z1, attv.y, p);
    p = fmaf(z2, attv.z, p);
    p = fmaf(z3, attv.w, p);
#pragma unroll
    for (int off = 32; off >= 1; off >>= 1) p += __shfl_xor(p, off, 64);
    // online softmax update
    const float mn = fmaxf(m, p);
    const float sc = __expf(m - mn);
    const float w = __expf(p - mn);
    ssum = fmaf(ssum, sc, w);
    a0 = fmaf(a0, sc, w * xs.x);
    a1 = fmaf(a1, sc, w * xs.y);
    a2 = fmaf(a2, sc, w * xs.z);
    a3 = fmaf(a3, sc, w * xs.w);
    m = mn;
  };

  // self loop first
  process(node, loopat + (size_t)node * DE);
  for (int j = r0; j < r1; ++j) {
    int e = __builtin_amdgcn_readfirstlane(csr[j]);
    int src = __builtin_amdgcn_readfirstlane(srcv[e]);
    process(src, eattr + (size_t)e * DE);
  }

  const float inv = 1.f / (ssum + 1e-16f);
  const float4 bv = *(const float4*)(bias + c0);
  float4 o;
  o.x = fmaf(a0, inv, bv.x);
  o.y = fmaf(a1, inv, bv.y);
  o.z = fmaf(a2, inv, bv.z);
  o.w = fmaf(a3, inv, bv.w);
  *(float4*)(hout + (size_t)node * HID + c0) = o;
}

// ---------------- layer-2 node transforms: xl2 = h@Wl2+bl2, xr2 = h@Wr2+br2 ----------------
// lanes 0-31 -> Wl2 cols, lanes 32-63 -> Wr2 cols; 8 rows per wave, 32 per block.

__global__ __launch_bounds__(256) void k_xform2(const float* __restrict__ h,
                                                const float* __restrict__ Wl,
                                                const float* __restrict__ bl,
                                                const float* __restrict__ Wr,
                                                const float* __restrict__ br,
                                                float* __restrict__ xl2,
                                                float* __restrict__ xr2) {
  const int t = threadIdx.x;
  const int c = t & 63;
  const int wv = t >> 6;
  const int cc = c & 31;
  const int r0 = blockIdx.x * 32 + wv * 8;
  const float* __restrict__ Wp = (c < 32) ? Wl : Wr;
  const float* __restrict__ bp = (c < 32) ? bl : br;
  float* __restrict__ op = (c < 32) ? xl2 : xr2;

  int rr[8];
#pragma unroll
  for (int i = 0; i < 8; ++i) {
    int r = r0 + i;
    rr[i] = r < NN ? r : NN - 1;
  }
  float acc[8];
#pragma unroll
  for (int i = 0; i < 8; ++i) acc[i] = 0.f;
#pragma unroll 4
  for (int k = 0; k < HID; ++k) {
    const float wval = Wp[k * OUTD + cc];
#pragma unroll
    for (int i = 0; i < 8; ++i) {
      acc[i] = fmaf(h[(size_t)rr[i] * HID + k], wval, acc[i]);
    }
  }
  const float bb = bp[cc];
#pragma unroll
  for (int i = 0; i < 8; ++i) {
    int r = r0 + i;
    if (r < NN) op[(size_t)r * OUTD + cc] = acc[i] + bb;
  }
}

// ---------------- layer-2 fused edge kernel + node-mean partials ----------------
// wave per node; lane: c = lane&31, k-half = lane>>5 splits the 16-d ee sum.

__global__ __launch_bounds__(256) void k_edge2(
    const float* __restrict__ xl2, const float* __restrict__ xr2,
    const float* __restrict__ eattr, const float* __restrict__ loopat,
    const int* __restrict__ srcv, const int* __restrict__ rowptr,
    const int* __restrict__ csr, const float* __restrict__ We2,
    const float* __restrict__ att2, float* __restrict__ partials) {
  __shared__ float sacc[OUTD];
  const int tid = threadIdx.x;
  const int lane = tid & 63;
  const int wid = tid >> 6;
  const int node = blockIdx.x * 4 + wid;
  const int c = lane & 31;
  const int kh = lane >> 5;

  if (tid < OUTD) sacc[tid] = 0.f;
  __syncthreads();

  float we2[8];
#pragma unroll
  for (int k = 0; k < 8; ++k) we2[k] = We2[(kh * 8 + k) * OUTD + c];
  const float attc = att2[c];
  const float xrc = xr2[(size_t)node * OUTD + c];
  const int r0 = rowptr[node], r1 = rowptr[node + 1];

  float m = -3.0e38f, ssum = 0.f, acc = 0.f;

  auto process = [&](int src, const float* __restrict__ eap) {
    const float xs = xl2[(size_t)src * OUTD + c];
    float ee = 0.f;
#pragma unroll
    for (int k = 0; k < 8; ++k) ee = fmaf(eap[kh * 8 + k], we2[k], ee);
    ee += __shfl_xor(ee, 32, 64);  // combine k-halves
    float z = xs + xrc + ee;
    z = z > 0.f ? z : SLOPE * z;
    float p = z * attc;
#pragma unroll
    for (int off = 16; off >= 1; off >>= 1) p += __shfl_xor(p, off, 64);
    const float mn = fmaxf(m, p);
    const float sc = __expf(m - mn);
    const float w = __expf(p - mn);
    ssum = fmaf(ssum, sc, w);
    acc = fmaf(acc, sc, w * xs);
    m = mn;
  };

  process(node, loopat + (size_t)node * DE);
  for (int j = r0; j < r1; ++j) {
    int e = __builtin_amdgcn_readfirstlane(csr[j]);
    int src = __builtin_amdgcn_readfirstlane(srcv[e]);
    process(src, eattr + (size_t)e * DE);
  }

  const float h2 = acc / (ssum + 1e-16f);
  if (lane < OUTD) atomicAdd(&sacc[c], h2);
  __syncthreads();
  if (tid < OUTD) partials[(size_t)blockIdx.x * OUTD + tid] = sacc[tid];
}

// ---------------- final mean over nodes + bias2 ----------------

__global__ __launch_bounds__(256) void k_final(const float* __restrict__ partials,
                                               const float* __restrict__ bias2,
                                               float* __restrict__ out, int nblk) {
  __shared__ float lds[256];
  const int cch = blockIdx.x;  // 0..31
  const int t = threadIdx.x;
  float s = 0.f;
  for (int b = t; b < nblk; b += 256) s += partials[(size_t)b * OUTD + cch];
  lds[t] = s;
  __syncthreads();
  for (int off = 128; off >= 1; off >>= 1) {
    if (t < off) lds[t] += lds[t + off];
    __syncthreads();
  }
  if (t == 0) out[cch] = lds[0] * (1.f / (float)NN) + bias2[cch];
}

// ---------------- host ----------------

static inline size_t alup(size_t x) { return (x + 255) & ~(size_t)255; }

extern "C" void kernel_launch(void* const* d_in, const int* in_sizes, int n_in,
                              void* d_out, int out_size, void* d_ws, size_t ws_size,
                              hipStream_t stream) {
  (void)in_sizes; (void)n_in; (void)out_size; (void)ws_size;
  const float* x = (const float*)d_in[0];
  const int* ei = (const int*)d_in[1];
  const float* ea = (const float*)d_in[2];
  const float* Wl1 = (const float*)d_in[3];
  const float* bl1 = (const float*)d_in[4];
  const float* Wr1 = (const float*)d_in[5];
  const float* br1 = (const float*)d_in[6];
  const float* We1 = (const float*)d_in[7];
  const float* att1 = (const float*)d_in[8];
  const float* bias1 = (const float*)d_in[9];
  const float* Wl2 = (const float*)d_in[10];
  const float* bl2 = (const float*)d_in[11];
  const float* Wr2 = (const float*)d_in[12];
  const float* br2 = (const float*)d_in[13];
  const float* We2 = (const float*)d_in[14];
  const float* att2 = (const float*)d_in[15];
  const float* bias2 = (const float*)d_in[16];
  const int* srcv = ei;
  const int* dstv = ei + NE;

  char* w = (char*)d_ws;
  int* deg = (int*)w;        w += alup((size_t)NN * 4);
  int* fill = (int*)w;       w += alup((size_t)NN * 4);
  int* rowptr = (int*)w;     w += alup((size_t)(NN + 1) * 4);
  int* csr = (int*)w;        w += alup((size_t)NE * 4);
  float* loopat = (float*)w; w += alup((size_t)NN * DE * 4);
  float* xl1 = (float*)w;    w += alup((size_t)NN * HID * 4);
  float* xr1 = (float*)w;    w += alup((size_t)NN * HID * 4);
  float* h = (float*)w;      w += alup((size_t)NN * HID * 4);
  float* partials = (float*)w;  // 12500*32 floats
  // xl2/xr2 reuse xl1/xr1 (dead after k_edge1)
  float* xl2 = xl1;
  float* xr2 = xr1;

  float* out = (float*)d_out;
  const int nblkE = (NE + 255) / 256;           // 3125
  const int nblkNode4 = NN / 4;                 // 12500

  hipMemsetAsync(deg, 0, (size_t)NN * 4, stream);
  hipMemsetAsync(fill, 0, (size_t)NN * 4, stream);

  k_count<<<nblkE, 256, 0, stream>>>(dstv, deg);
  k_scan<<<1, 1024, 0, stream>>>(deg, rowptr);
  k_fill<<<nblkE, 256, 0, stream>>>(dstv, rowptr, fill, csr);
  k_loopattr<<<(NN * DE + 255) / 256, 256, 0, stream>>>(ea, rowptr, csr, loopat);

  k_xform1<<<NN / 16, 256, 0, stream>>>(x, Wl1, bl1, Wr1, br1, xl1, xr1);
  k_edge1<<<nblkNode4, 256, 0, stream>>>(xl1, xr1, ea, loopat, srcv, rowptr, csr,
                                         We1, att1, bias1, h);
  k_xform2<<<(NN + 31) / 32, 256, 0, stream>>>(h, Wl2, bl2, Wr2, br2, xl2, xr2);
  k_edge2<<<nblkNode4, 256, 0, stream>>>(xl2, xr2, ea, loopat, srcv, rowptr, csr,
                                         We2, att2, partials);
  k_final<<<OUTD, 256, 0, stream>>>(partials, bias2, out, nblkNode4);
}

// Round 2
// 708.202 us; speedup vs baseline: 1.2627x; 1.2627x over previous
//
#include <hip/hip_runtime.h>
#include <hip/hip_bf16.h>
#include <stdint.h>

// GATv2 x2 fused pipeline, fp32 end-to-end.
// N=50000 nodes, E=800000 edges, 128 -> 256 -> 32, mean over nodes -> [32].

#define NN 50000
#define NE 800000
#define DIN 128
#define DE 16
#define HID 256
#define OUTD 32
#define SLOPE 0.2f

__device__ __forceinline__ float rfl(float x) {
  return __int_as_float(__builtin_amdgcn_readfirstlane(__float_as_int(x)));
}

// ---------------- CSR build ----------------

__global__ void k_count(const int* __restrict__ dstv, int* __restrict__ deg) {
  int e = blockIdx.x * 256 + threadIdx.x;
  if (e < NE) atomicAdd(&deg[dstv[e]], 1);
}

__global__ __launch_bounds__(1024) void k_scan(const int* __restrict__ deg,
                                               int* __restrict__ rowptr) {
  __shared__ int lds[1024];
  const int t = threadIdx.x;
  const int CH = 49;  // ceil(50000/1024)
  const int base = t * CH;
  int s = 0;
  for (int i = 0; i < CH; ++i) {
    int idx = base + i;
    if (idx < NN) s += deg[idx];
  }
  lds[t] = s;
  __syncthreads();
  int v = s;
  for (int off = 1; off < 1024; off <<= 1) {
    int add = (t >= off) ? lds[t - off] : 0;
    __syncthreads();
    v += add;
    lds[t] = v;
    __syncthreads();
  }
  int run = v - s;  // exclusive prefix
  for (int i = 0; i < CH; ++i) {
    int idx = base + i;
    if (idx < NN) {
      rowptr[idx] = run;
      run += deg[idx];
    }
  }
  if (t == 1023) rowptr[NN] = run;
}

// store (edge_id, src) packed per CSR slot
__global__ void k_fill(const int* __restrict__ srcv, const int* __restrict__ dstv,
                       const int* __restrict__ rowptr, int* __restrict__ fill,
                       int2* __restrict__ es) {
  int e = blockIdx.x * 256 + threadIdx.x;
  if (e < NE) {
    int d = dstv[e];
    int p = atomicAdd(&fill[d], 1);
    es[rowptr[d] + p] = make_int2(e, srcv[e]);
  }
}

// self-loop attr = mean of incoming edge_attr (0 if no in-edges)
__global__ void k_loopattr(const float* __restrict__ ea, const int* __restrict__ rowptr,
                           const int2* __restrict__ es, float* __restrict__ loopat) {
  int g = blockIdx.x * 256 + threadIdx.x;
  if (g >= NN * DE) return;
  int n = g >> 4, d = g & 15;
  int r0 = rowptr[n], r1 = rowptr[n + 1];
  float s = 0.f;
  for (int j = r0; j < r1; ++j) {
    int e = es[j].x;
    s += ea[(size_t)e * DE + d];
  }
  int dg = r1 - r0;
  loopat[g] = s / (float)(dg > 0 ? dg : 1);
}

// ---------------- layer-1 node transforms ----------------

__global__ __launch_bounds__(256) void k_xform1(const float* __restrict__ x,
                                                const float* __restrict__ Wl,
                                                const float* __restrict__ bl,
                                                const float* __restrict__ Wr,
                                                const float* __restrict__ br,
                                                float* __restrict__ xl,
                                                float* __restrict__ xr) {
  const int c = threadIdx.x;
  const int r0 = blockIdx.x * 16;
  float accl[16], accr[16];
#pragma unroll
  for (int r = 0; r < 16; ++r) { accl[r] = 0.f; accr[r] = 0.f; }
  const float* __restrict__ xb = x + (size_t)r0 * DIN;
#pragma unroll 4
  for (int k = 0; k < DIN; ++k) {
    const float wl = Wl[k * HID + c];
    const float wr = Wr[k * HID + c];
#pragma unroll
    for (int r = 0; r < 16; ++r) {
      const float xv = xb[r * DIN + k];
      accl[r] = fmaf(xv, wl, accl[r]);
      accr[r] = fmaf(xv, wr, accr[r]);
    }
  }
  const float blc = bl[c], brc = br[c];
#pragma unroll
  for (int r = 0; r < 16; ++r) {
    xl[(size_t)(r0 + r) * HID + c] = accl[r] + blc;
    xr[(size_t)(r0 + r) * HID + c] = accr[r] + brc;
  }
}

// ---------------- layer-1 fused edge kernel: wave/node, online softmax, unroll-4 ----------------

__global__ __launch_bounds__(256) void k_edge1(
    const float* __restrict__ xl, const float* __restrict__ xr,
    const float* __restrict__ eattr, const float* __restrict__ loopat,
    const int* __restrict__ rowptr, const int2* __restrict__ es,
    const float* __restrict__ We, const float* __restrict__ att,
    const float* __restrict__ bias, float* __restrict__ hout) {
  const int tid = threadIdx.x;
  const int lane = tid & 63;
  const int wid = tid >> 6;
  const int node = blockIdx.x * 4 + wid;
  const int c0 = lane << 2;  // 4 channels per lane

  float we[DE][4];
#pragma unroll
  for (int k = 0; k < DE; ++k) {
    const float4 w4 = *(const float4*)(We + k * HID + c0);
    we[k][0] = w4.x; we[k][1] = w4.y; we[k][2] = w4.z; we[k][3] = w4.w;
  }
  const float4 attv = *(const float4*)(att + c0);
  const float4 xrv = *(const float4*)(xr + (size_t)node * HID + c0);
  const int r0 = rowptr[node], r1 = rowptr[node + 1];

  float m = -3.0e38f, ssum = 0.f;
  float a0 = 0.f, a1 = 0.f, a2 = 0.f, a3 = 0.f;

  // per-lane partial score (pre-reduce); ea values scalarized (wave-uniform)
  auto pscore = [&](const float* __restrict__ eap, const float4 xs) -> float {
    const float4* __restrict__ eb = (const float4*)eap;
    const float4 A0 = eb[0], A1 = eb[1], A2 = eb[2], A3 = eb[3];
    float a[16] = {rfl(A0.x), rfl(A0.y), rfl(A0.z), rfl(A0.w),
                   rfl(A1.x), rfl(A1.y), rfl(A1.z), rfl(A1.w),
                   rfl(A2.x), rfl(A2.y), rfl(A2.z), rfl(A2.w),
                   rfl(A3.x), rfl(A3.y), rfl(A3.z), rfl(A3.w)};
    float e0 = 0.f, e1 = 0.f, e2 = 0.f, e3 = 0.f;
#pragma unroll
    for (int k = 0; k < DE; ++k) {
      e0 = fmaf(a[k], we[k][0], e0);
      e1 = fmaf(a[k], we[k][1], e1);
      e2 = fmaf(a[k], we[k][2], e2);
      e3 = fmaf(a[k], we[k][3], e3);
    }
    float z0 = xs.x + xrv.x + e0;
    float z1 = xs.y + xrv.y + e1;
    float z2 = xs.z + xrv.z + e2;
    float z3 = xs.w + xrv.w + e3;
    z0 = z0 > 0.f ? z0 : SLOPE * z0;
    z1 = z1 > 0.f ? z1 : SLOPE * z1;
    z2 = z2 > 0.f ? z2 : SLOPE * z2;
    z3 = z3 > 0.f ? z3 : SLOPE * z3;
    float p = z0 * attv.x;
    p = fmaf(z1, attv.y, p);
    p = fmaf(z2, attv.z, p);
    p = fmaf(z3, attv.w, p);
    return p;
  };

  auto upd = [&](float p, const float4 xs) {
    const float mn = fmaxf(m, p);
    const float sc = __expf(m - mn);
    const float w = __expf(p - mn);
    ssum = fmaf(ssum, sc, w);
    a0 = fmaf(a0, sc, w * xs.x);
    a1 = fmaf(a1, sc, w * xs.y);
    a2 = fmaf(a2, sc, w * xs.z);
    a3 = fmaf(a3, sc, w * xs.w);
    m = mn;
  };

  // self loop
  {
    const float4 xs = *(const float4*)(xl + (size_t)node * HID + c0);
    float p = pscore(loopat + (size_t)node * DE, xs);
#pragma unroll
    for (int off = 32; off >= 1; off >>= 1) p += __shfl_xor(p, off, 64);
    upd(p, xs);
  }

  int j = r0;
  for (; j + 4 <= r1; j += 4) {
    int e_[4], s_[4];
#pragma unroll
    for (int u = 0; u < 4; ++u) {
      const int2 q = es[j + u];
      e_[u] = __builtin_amdgcn_readfirstlane(q.x);
      s_[u] = __builtin_amdgcn_readfirstlane(q.y);
    }
    float4 xs[4];
#pragma unroll
    for (int u = 0; u < 4; ++u)
      xs[u] = *(const float4*)(xl + (size_t)s_[u] * HID + c0);
    float p[4];
#pragma unroll
    for (int u = 0; u < 4; ++u)
      p[u] = pscore(eattr + (size_t)e_[u] * DE, xs[u]);
#pragma unroll
    for (int off = 32; off >= 1; off >>= 1) {
#pragma unroll
      for (int u = 0; u < 4; ++u) p[u] += __shfl_xor(p[u], off, 64);
    }
#pragma unroll
    for (int u = 0; u < 4; ++u) upd(p[u], xs[u]);
  }
  for (; j < r1; ++j) {
    const int2 q = es[j];
    const int e = __builtin_amdgcn_readfirstlane(q.x);
    const int src = __builtin_amdgcn_readfirstlane(q.y);
    const float4 xs = *(const float4*)(xl + (size_t)src * HID + c0);
    float p = pscore(eattr + (size_t)e * DE, xs);
#pragma unroll
    for (int off = 32; off >= 1; off >>= 1) p += __shfl_xor(p, off, 64);
    upd(p, xs);
  }

  const float inv = 1.f / (ssum + 1e-16f);
  const float4 bv = *(const float4*)(bias + c0);
  float4 o;
  o.x = fmaf(a0, inv, bv.x);
  o.y = fmaf(a1, inv, bv.y);
  o.z = fmaf(a2, inv, bv.z);
  o.w = fmaf(a3, inv, bv.w);
  *(float4*)(hout + (size_t)node * HID + c0) = o;
}

// ---------------- layer-2 node transforms ----------------

__global__ __launch_bounds__(256) void k_xform2(const float* __restrict__ h,
                                                const float* __restrict__ Wl,
                                                const float* __restrict__ bl,
                                                const float* __restrict__ Wr,
                                                const float* __restrict__ br,
                                                float* __restrict__ xl2,
                                                float* __restrict__ xr2) {
  const int t = threadIdx.x;
  const int c = t & 63;
  const int wv = t >> 6;
  const int cc = c & 31;
  const int r0 = blockIdx.x * 32 + wv * 8;
  const float* __restrict__ Wp = (c < 32) ? Wl : Wr;
  const float* __restrict__ bp = (c < 32) ? bl : br;
  float* __restrict__ op = (c < 32) ? xl2 : xr2;

  int rr[8];
#pragma unroll
  for (int i = 0; i < 8; ++i) {
    int r = r0 + i;
    rr[i] = r < NN ? r : NN - 1;
  }
  float acc[8];
#pragma unroll
  for (int i = 0; i < 8; ++i) acc[i] = 0.f;
#pragma unroll 4
  for (int k = 0; k < HID; ++k) {
    const float wval = Wp[k * OUTD + cc];
#pragma unroll
    for (int i = 0; i < 8; ++i) {
      acc[i] = fmaf(h[(size_t)rr[i] * HID + k], wval, acc[i]);
    }
  }
  const float bb = bp[cc];
#pragma unroll
  for (int i = 0; i < 8; ++i) {
    int r = r0 + i;
    if (r < NN) op[(size_t)r * OUTD + cc] = acc[i] + bb;
  }
}

// ---------------- layer-2 fused edge kernel: wave/node, 2 edges in flight (half-waves) ----------------

__global__ __launch_bounds__(256) void k_edge2(
    const float* __restrict__ xl2, const float* __restrict__ xr2,
    const float* __restrict__ eattr, const float* __restrict__ loopat,
    const int* __restrict__ rowptr, const int2* __restrict__ es,
    const float* __restrict__ We2, const float* __restrict__ att2,
    float* __restrict__ partials) {
  __shared__ float sacc[OUTD];
  const int tid = threadIdx.x;
  const int lane = tid & 63;
  const int wid = tid >> 6;
  const int node = blockIdx.x * 4 + wid;
  const int c = lane & 31;
  const int half = lane >> 5;

  if (tid < OUTD) sacc[tid] = 0.f;
  __syncthreads();

  float we2[DE];
#pragma unroll
  for (int k = 0; k < DE; ++k) we2[k] = We2[k * OUTD + c];
  const float attc = att2[c];
  const float xrc = xr2[(size_t)node * OUTD + c];
  const int r0 = rowptr[node], r1 = rowptr[node + 1];

  // independent online-softmax state per half-wave
  float m = -3.0e38f, ssum = 0.f, acc = 0.f;

  auto proc = [&](int src, const float* __restrict__ eap) {
    const float xs = xl2[(size_t)src * OUTD + c];
    const float4* __restrict__ eb = (const float4*)eap;
    const float4 A0 = eb[0], A1 = eb[1], A2 = eb[2], A3 = eb[3];
    float ee = A0.x * we2[0];
    ee = fmaf(A0.y, we2[1], ee);
    ee = fmaf(A0.z, we2[2], ee);
    ee = fmaf(A0.w, we2[3], ee);
    ee = fmaf(A1.x, we2[4], ee);
    ee = fmaf(A1.y, we2[5], ee);
    ee = fmaf(A1.z, we2[6], ee);
    ee = fmaf(A1.w, we2[7], ee);
    ee = fmaf(A2.x, we2[8], ee);
    ee = fmaf(A2.y, we2[9], ee);
    ee = fmaf(A2.z, we2[10], ee);
    ee = fmaf(A2.w, we2[11], ee);
    ee = fmaf(A3.x, we2[12], ee);
    ee = fmaf(A3.y, we2[13], ee);
    ee = fmaf(A3.z, we2[14], ee);
    ee = fmaf(A3.w, we2[15], ee);
    float z = xs + xrc + ee;
    z = z > 0.f ? z : SLOPE * z;
    float p = z * attc;
#pragma unroll
    for (int off = 16; off >= 1; off >>= 1) p += __shfl_xor(p, off, 64);
    const float mn = fmaxf(m, p);
    const float sc = __expf(m - mn);
    const float w = __expf(p - mn);
    ssum = fmaf(ssum, sc, w);
    acc = fmaf(acc, sc, w * xs);
    m = mn;
  };

  // self-loop handled by half 0; csr slots interleaved even/odd between halves
  if (half == 0) proc(node, loopat + (size_t)node * DE);
  int j = r0 + half;
  for (; j + 2 < r1; j += 4) {
    {
      const int2 q = es[j];
      proc(q.y, eattr + (size_t)q.x * DE);
    }
    {
      const int2 q = es[j + 2];
      proc(q.y, eattr + (size_t)q.x * DE);
    }
  }
  for (; j < r1; j += 2) {
    const int2 q = es[j];
    proc(q.y, eattr + (size_t)q.x * DE);
  }

  // merge the two half-wave states (associative online-softmax merge)
  const float mo = __shfl_xor(m, 32, 64);
  const float so = __shfl_xor(ssum, 32, 64);
  const float ao = __shfl_xor(acc, 32, 64);
  const float mn = fmaxf(m, mo);
  const float sc0 = __expf(m - mn);
  const float sc1 = __expf(mo - mn);
  const float S = ssum * sc0 + so * sc1;
  const float A = acc * sc0 + ao * sc1;
  const float h2 = A / (S + 1e-16f);

  if (lane < OUTD) atomicAdd(&sacc[c], h2);
  __syncthreads();
  if (tid < OUTD) partials[(size_t)blockIdx.x * OUTD + tid] = sacc[tid];
}

// ---------------- final mean over nodes + bias2 ----------------

__global__ __launch_bounds__(256) void k_final(const float* __restrict__ partials,
                                               const float* __restrict__ bias2,
                                               float* __restrict__ out, int nblk) {
  __shared__ float lds[256];
  const int cch = blockIdx.x;  // 0..31
  const int t = threadIdx.x;
  float s = 0.f;
  for (int b = t; b < nblk; b += 256) s += partials[(size_t)b * OUTD + cch];
  lds[t] = s;
  __syncthreads();
  for (int off = 128; off >= 1; off >>= 1) {
    if (t < off) lds[t] += lds[t + off];
    __syncthreads();
  }
  if (t == 0) out[cch] = lds[0] * (1.f / (float)NN) + bias2[cch];
}

// ---------------- host ----------------

static inline size_t alup(size_t x) { return (x + 255) & ~(size_t)255; }

extern "C" void kernel_launch(void* const* d_in, const int* in_sizes, int n_in,
                              void* d_out, int out_size, void* d_ws, size_t ws_size,
                              hipStream_t stream) {
  (void)in_sizes; (void)n_in; (void)out_size; (void)ws_size;
  const float* x = (const float*)d_in[0];
  const int* ei = (const int*)d_in[1];
  const float* ea = (const float*)d_in[2];
  const float* Wl1 = (const float*)d_in[3];
  const float* bl1 = (const float*)d_in[4];
  const float* Wr1 = (const float*)d_in[5];
  const float* br1 = (const float*)d_in[6];
  const float* We1 = (const float*)d_in[7];
  const float* att1 = (const float*)d_in[8];
  const float* bias1 = (const float*)d_in[9];
  const float* Wl2 = (const float*)d_in[10];
  const float* bl2 = (const float*)d_in[11];
  const float* Wr2 = (const float*)d_in[12];
  const float* br2 = (const float*)d_in[13];
  const float* We2 = (const float*)d_in[14];
  const float* att2 = (const float*)d_in[15];
  const float* bias2 = (const float*)d_in[16];
  const int* srcv = ei;
  const int* dstv = ei + NE;

  char* w = (char*)d_ws;
  int* deg = (int*)w;        w += alup((size_t)NN * 4);
  int* fill = (int*)w;       w += alup((size_t)NN * 4);
  int* rowptr = (int*)w;     w += alup((size_t)(NN + 1) * 4);
  int2* es = (int2*)w;       w += alup((size_t)NE * 8);
  float* loopat = (float*)w; w += alup((size_t)NN * DE * 4);
  float* xl1 = (float*)w;    w += alup((size_t)NN * HID * 4);
  float* xr1 = (float*)w;    w += alup((size_t)NN * HID * 4);
  float* h = (float*)w;      w += alup((size_t)NN * HID * 4);
  float* partials = (float*)w;  // 12500*32 floats
  float* xl2 = xl1;
  float* xr2 = xr1;

  float* out = (float*)d_out;
  const int nblkE = (NE + 255) / 256;  // 3125
  const int nblkNode4 = NN / 4;        // 12500

  hipMemsetAsync(deg, 0, (size_t)NN * 4, stream);
  hipMemsetAsync(fill, 0, (size_t)NN * 4, stream);

  k_count<<<nblkE, 256, 0, stream>>>(dstv, deg);
  k_scan<<<1, 1024, 0, stream>>>(deg, rowptr);
  k_fill<<<nblkE, 256, 0, stream>>>(srcv, dstv, rowptr, fill, es);
  k_loopattr<<<(NN * DE + 255) / 256, 256, 0, stream>>>(ea, rowptr, es, loopat);

  k_xform1<<<NN / 16, 256, 0, stream>>>(x, Wl1, bl1, Wr1, br1, xl1, xr1);
  k_edge1<<<nblkNode4, 256, 0, stream>>>(xl1, xr1, ea, loopat, rowptr, es,
                                         We1, att1, bias1, h);
  k_xform2<<<(NN + 31) / 32, 256, 0, stream>>>(h, Wl2, bl2, Wr2, br2, xl2, xr2);
  k_edge2<<<nblkNode4, 256, 0, stream>>>(xl2, xr2, ea, loopat, rowptr, es,
                                         We2, att2, partials);
  k_final<<<OUTD, 256, 0, stream>>>(partials, bias2, out, nblkNode4);
}